// Round 10
// baseline (121.868 us; speedup 1.0000x reference)
//
#include <hip/hip_runtime.h>

typedef float f32x4 __attribute__((ext_vector_type(4)));

constexpr int TB = 256;
constexpr int BANDS = 28;
constexpr int NN = 512;
constexpr int W = NN + BANDS - 1;        // 539
constexpr int NB = 8;
constexpr int NR = 512;
constexpr int ROWS = NB * NR;            // 4096
constexpr long long OUT_HALF = (long long)ROWS * NN * BANDS;   // 58,720,256
constexpr int NSLOT = 64;                // atomicMax slot count per tensor
constexpr int V4_PER_ROW = NN * BANDS / 4;  // 3584
constexpr int NCH = 19;                  // ceil(512/28) chunks of width 28

// Chunked-scan (Gil-Werman) helpers: window width == chunk width (28), so any
// window [j-27, j] is a suffix of one chunk + prefix of the next (or clipped).

// ---------------- stage-1: windowed maxima only -> atomic slots ----------------
// MODE 1: slot atomics. MODE 0: 2-word atomic fallback (ws < 512B).
template <int MODE>
__global__ __launch_bounds__(TB) void stage1_kernel(const float* __restrict__ inputs,
                                                    const float* __restrict__ mask,
                                                    float* __restrict__ wsf) {
  __shared__ __align__(16) float sMB[NN], sM0[NN];
  __shared__ __align__(16) float sF[NN], sB[NN];    // chunked prefix/suffix sums of msq
  __shared__ __align__(16) float sFm[NN], sBm[NN];  // chunked prefix/suffix max of m0
  __shared__ float red[8];
  const int row = blockIdx.x;
  const int r = row & (NR - 1);
  const int tid = threadIdx.x;

  const float* Yg = inputs + (long long)row * W;
  const f32x4* m04 = reinterpret_cast<const f32x4*>(mask + (long long)r * NN);
  const f32x4* mb4 = reinterpret_cast<const f32x4*>(mask + (long long)row * NN);
  for (int k = tid; k < NN / 4; k += TB) {
    reinterpret_cast<f32x4*>(sMB)[k] = mb4[k];
    reinterpret_cast<f32x4*>(sM0)[k] = m04[k];
  }
  __syncthreads();

  if (tid < 4 * NCH) {   // 76 independent chunk-scan tasks
    const int arr = tid / NCH;
    const int ch  = tid - arr * NCH;
    const int cs  = ch * 28;
    const int n   = (ch == NCH - 1) ? (NN - cs) : 28;
    if (arr == 0) {
      float run = 0.f;
      for (int i = 0; i < n; ++i) { float v = sMB[cs + i]; run += v * v; sF[cs + i] = run; }
    } else if (arr == 1) {
      float run = 0.f;
      for (int i = n - 1; i >= 0; --i) { float v = sMB[cs + i]; run += v * v; sB[cs + i] = run; }
    } else if (arr == 2) {
      float run = 0.f;
      for (int i = 0; i < n; ++i) { run = fmaxf(run, sM0[cs + i]); sFm[cs + i] = run; }
    } else {
      float run = 0.f;
      for (int i = n - 1; i >= 0; --i) { run = fmaxf(run, sM0[cs + i]); sBm[cs + i] = run; }
    }
  }
  __syncthreads();

  float lmax = 0.f, lmax1 = 0.f;
  for (int j = tid; j < W; j += TB) {
    int lo = j - (BANDS - 1); if (lo < 0) lo = 0;
    int hi = j;               if (hi > NN - 1) hi = NN - 1;
    const int a = lo / 28, b = hi / 28;
    float slide, wm;
    if (a == b) {
      const bool atStart = (lo == a * 28);
      slide = atStart ? sF[hi] : sB[lo];
      wm    = atStart ? sFm[hi] : sBm[lo];
    } else {
      slide = sB[lo] + sF[hi];
      wm    = fmaxf(sBm[lo], sFm[hi]);
    }
    const float y  = Yg[j];                       // coalesced global read
    const float y1 = y * (1.0f / (slide + 1.0f));
    lmax  = fmaxf(lmax,  wm * y);                 // exact: fl monotone per operand
    lmax1 = fmaxf(lmax1, wm * y1);
  }
  for (int off = 32; off > 0; off >>= 1) {
    lmax  = fmaxf(lmax,  __shfl_down(lmax,  off));
    lmax1 = fmaxf(lmax1, __shfl_down(lmax1, off));
  }
  const int wid = tid >> 6;
  if ((tid & 63) == 0) { red[wid] = lmax; red[4 + wid] = lmax1; }
  __syncthreads();
  if (tid == 0) {
    float m  = fmaxf(fmaxf(red[0], red[1]), fmaxf(red[2], red[3]));
    float m1 = fmaxf(fmaxf(red[4], red[5]), fmaxf(red[6], red[7]));
    // values >= 0: int order == float order; max is order-independent and
    // idempotent across timed replays (stale == final).
    if (MODE == 0) {
      atomicMax((int*)wsf + 0, __float_as_int(m));
      atomicMax((int*)wsf + 1, __float_as_int(m1));
    } else {
      const int slot = row & (NSLOT - 1);
      atomicMax((int*)wsf + slot,         __float_as_int(m));
      atomicMax((int*)wsf + NSLOT + slot, __float_as_int(m1));
    }
  }
}

__global__ void init_ws_kernel(int* ws) {
  if (threadIdx.x < 2) ws[threadIdx.x] = 0;
}

// ---------------- stage-2: recompute Yg1 via chunked scans, write both tensors ----------------
// RM 1: reduce slot maxima. RM 0: read ws[0..1].
template <int RM>
__global__ __launch_bounds__(TB) void write_kernel(const float* __restrict__ inputs,
                                                   const float* __restrict__ mask,
                                                   const float* __restrict__ wsf,
                                                   float* __restrict__ out) {
  __shared__ __align__(16) float sY[W + 1], sY1[W + 1], sM0[NN], sMB[NN];
  __shared__ __align__(16) float sF[NN], sB[NN];
  const int row = blockIdx.x;
  const int r = row & (NR - 1);
  const int tid = threadIdx.x;

  const float* Yg = inputs + (long long)row * W;
  const float* m0 = mask + (long long)r * NN;
  const float* mb = mask + (long long)row * NN;
  for (int k = tid; k < W; k += TB) sY[k] = Yg[k];
  for (int k = tid; k < NN; k += TB) { sM0[k] = m0[k]; sMB[k] = mb[k]; }

  float invX, invX1;
  if (RM == 0) {
    invX  = 1.0f / __int_as_float(((const int*)wsf)[0]);
    invX1 = 1.0f / __int_as_float(((const int*)wsf)[1]);
  } else {
    const int* slots = (const int*)wsf;
    float m = 0.f, m1 = 0.f;
#pragma unroll
    for (int i = 0; i < NSLOT; ++i) {
      m  = fmaxf(m,  __int_as_float(slots[i]));
      m1 = fmaxf(m1, __int_as_float(slots[NSLOT + i]));
    }
    invX = 1.0f / m;
    invX1 = 1.0f / m1;
  }
  __syncthreads();

  if (tid < 2 * NCH) {   // sum scans only (maxima come from slots)
    const int arr = tid / NCH;
    const int ch  = tid - arr * NCH;
    const int cs  = ch * 28;
    const int n   = (ch == NCH - 1) ? (NN - cs) : 28;
    if (arr == 0) {
      float run = 0.f;
      for (int i = 0; i < n; ++i) { float v = sMB[cs + i]; run += v * v; sF[cs + i] = run; }
    } else {
      float run = 0.f;
      for (int i = n - 1; i >= 0; --i) { float v = sMB[cs + i]; run += v * v; sB[cs + i] = run; }
    }
  }
  __syncthreads();

  for (int j = tid; j < W; j += TB) {
    int lo = j - (BANDS - 1); if (lo < 0) lo = 0;
    int hi = j;               if (hi > NN - 1) hi = NN - 1;
    const int a = lo / 28, b = hi / 28;
    float slide;
    if (a == b) {
      slide = (lo == a * 28) ? sF[hi] : sB[lo];
    } else {
      slide = sB[lo] + sF[hi];
    }
    sY1[j] = sY[j] * (1.0f / (slide + 1.0f));
  }
  __syncthreads();

  f32x4* outX  = reinterpret_cast<f32x4*>(out) + (long long)row * V4_PER_ROW;
  f32x4* outX1 = reinterpret_cast<f32x4*>(out + OUT_HALF) + (long long)row * V4_PER_ROW;
  for (int idx = tid; idx < V4_PER_ROW; idx += TB) {
    int c = idx / 7;
    int q = idx - c * 7;
    int j0 = c + q * 4;
    float mm = sM0[c];
    f32x4 vx, vx1;
    vx.x  = (mm * sY[j0 + 0]) * invX;
    vx.y  = (mm * sY[j0 + 1]) * invX;
    vx.z  = (mm * sY[j0 + 2]) * invX;
    vx.w  = (mm * sY[j0 + 3]) * invX;
    vx1.x = (mm * sY1[j0 + 0]) * invX1;
    vx1.y = (mm * sY1[j0 + 1]) * invX1;
    vx1.z = (mm * sY1[j0 + 2]) * invX1;
    vx1.w = (mm * sY1[j0 + 3]) * invX1;
    outX[idx]  = vx;
    outX1[idx] = vx1;
  }
}

extern "C" void kernel_launch(void* const* d_in, const int* in_sizes, int n_in,
                              void* d_out, int out_size, void* d_ws, size_t ws_size,
                              hipStream_t stream) {
  const float* inputs = (const float*)d_in[0];
  const float* mask   = (const float*)d_in[1];
  float* wsf = (float*)d_ws;
  float* out = (float*)d_out;

  const size_t need_slots = (size_t)(2 * NSLOT) * sizeof(int);   // 512 B

  if (ws_size >= need_slots) {
    hipLaunchKernelGGL(stage1_kernel<1>, dim3(ROWS), dim3(TB), 0, stream, inputs, mask, wsf);
    hipLaunchKernelGGL(write_kernel<1>, dim3(ROWS), dim3(TB), 0, stream, inputs, mask, wsf, out);
  } else {
    hipLaunchKernelGGL(init_ws_kernel, dim3(1), dim3(64), 0, stream, (int*)d_ws);
    hipLaunchKernelGGL(stage1_kernel<0>, dim3(ROWS), dim3(TB), 0, stream, inputs, mask, wsf);
    hipLaunchKernelGGL(write_kernel<0>, dim3(ROWS), dim3(TB), 0, stream, inputs, mask, wsf, out);
  }
}

// Round 11
// 119.174 us; speedup vs baseline: 1.0226x; 1.0226x over previous
//
#include <hip/hip_runtime.h>

typedef float f32x4 __attribute__((ext_vector_type(4)));

constexpr int TB = 256;
constexpr int BANDS = 28;
constexpr int NN = 512;
constexpr int W = NN + BANDS - 1;        // 539
constexpr int NB = 8;
constexpr int NR = 512;
constexpr int ROWS = NB * NR;            // 4096
constexpr long long OUT_HALF = (long long)ROWS * NN * BANDS;   // 58,720,256
constexpr int NSLOT = 64;                // atomicMax slot count per tensor
constexpr int V4_PER_ROW = NN * BANDS / 4;  // 3584
constexpr int NCH = 19;                  // ceil(512/28) chunks of width 28

// ---------------- stage-1: r-shared (512 blocks; 4 waves x 2 rows = 8 b's per r) ----------------
// Chunked-scan (Gil-Werman): window width == chunk width (28), so window [j-27,j]
// = suffix of one chunk + prefix of the next (or a clipped single-chunk case).
// MODE 1: per-wave maxima -> 64 atomic slots. MODE 0: block maxima -> ws[0..1].
template <int MODE>
__global__ __launch_bounds__(TB) void stage1_kernel(const float* __restrict__ inputs,
                                                    const float* __restrict__ mask,
                                                    float* __restrict__ wsf) {
  __shared__ __align__(16) float sM0[NN], sFm[NN], sBm[NN];       // shared per-r
  __shared__ __align__(16) float sMB[4][NN], sF[4][NN], sB[4][NN]; // wave-private
  __shared__ float red[8];
  const int r   = blockIdx.x;
  const int tid = threadIdx.x;
  const int wv  = tid >> 6;
  const int ln  = tid & 63;

  // stage m0 once per r (vectorized)
  const f32x4* m04 = reinterpret_cast<const f32x4*>(mask + (long long)r * NN);
  for (int k = tid; k < NN / 4; k += TB) reinterpret_cast<f32x4*>(sM0)[k] = m04[k];
  __syncthreads();

  // m0 chunk max-scans: 38 tasks, computed ONCE per r (was 8x redundant)
  if (tid < 2 * NCH) {
    const int arr = tid / NCH, ch = tid - arr * NCH;
    const int cs = ch * 28, n = (ch == NCH - 1) ? NN - cs : 28;
    if (arr == 0) { float run = 0.f; for (int i = 0; i < n; ++i) { run = fmaxf(run, sM0[cs + i]); sFm[cs + i] = run; } }
    else          { float run = 0.f; for (int i = n - 1; i >= 0; --i) { run = fmaxf(run, sM0[cs + i]); sBm[cs + i] = run; } }
  }

  float lmax = 0.f, lmax1 = 0.f;

  for (int h = 0; h < 2; ++h) {
    const int b = wv * 2 + h;
    const long long row = (long long)b * NR + r;
    // wave-local mb load: 64 lanes x 2 f32x4
    const f32x4* mb4 = reinterpret_cast<const f32x4*>(mask + row * NN);
    reinterpret_cast<f32x4*>(sMB[wv])[ln]      = mb4[ln];
    reinterpret_cast<f32x4*>(sMB[wv])[ln + 64] = mb4[ln + 64];
    __syncthreads();                     // mb visible (also covers m0-scan on h=0)

    // wave-local chunk sum scans of mb^2: 38 tasks on 64 lanes
    if (ln < 2 * NCH) {
      const int arr = ln / NCH, ch = ln - arr * NCH;
      const int cs = ch * 28, n = (ch == NCH - 1) ? NN - cs : 28;
      if (arr == 0) { float run = 0.f; for (int i = 0; i < n; ++i) { float v = sMB[wv][cs + i]; run += v * v; sF[wv][cs + i] = run; } }
      else          { float run = 0.f; for (int i = n - 1; i >= 0; --i) { float v = sMB[wv][cs + i]; run += v * v; sB[wv][cs + i] = run; } }
    }
    __syncthreads();                     // scans visible

    const float* Yg = inputs + row * W;
    for (int j = ln; j < W; j += 64) {
      int lo = j - (BANDS - 1); if (lo < 0) lo = 0;
      int hi = j;               if (hi > NN - 1) hi = NN - 1;
      const int a = lo / 28, bb = hi / 28;
      float slide, wm;
      if (a == bb) {
        const bool atStart = (lo == a * 28);
        slide = atStart ? sF[wv][hi] : sB[wv][lo];
        wm    = atStart ? sFm[hi] : sBm[lo];
      } else {
        slide = sB[wv][lo] + sF[wv][hi];
        wm    = fmaxf(sBm[lo], sFm[hi]);
      }
      const float y  = Yg[j];                    // coalesced global read
      const float y1 = y * (1.0f / (slide + 1.0f));
      lmax  = fmaxf(lmax,  wm * y);              // exact: fl monotone per operand
      lmax1 = fmaxf(lmax1, wm * y1);
    }
    __syncthreads();                     // protect scan-buffer reuse next h
  }

  for (int off = 32; off > 0; off >>= 1) {
    lmax  = fmaxf(lmax,  __shfl_down(lmax,  off));
    lmax1 = fmaxf(lmax1, __shfl_down(lmax1, off));
  }
  // values >= 0: int order == float order; max is order-independent and
  // idempotent across timed replays (stale == final).
  if (MODE == 1) {
    if (ln == 0) {
      const int slot = ((r << 2) | wv) & (NSLOT - 1);
      atomicMax((int*)wsf + slot,         __float_as_int(lmax));
      atomicMax((int*)wsf + NSLOT + slot, __float_as_int(lmax1));
    }
  } else {
    if (ln == 0) { red[wv] = lmax; red[4 + wv] = lmax1; }
    __syncthreads();
    if (tid == 0) {
      float m  = fmaxf(fmaxf(red[0], red[1]), fmaxf(red[2], red[3]));
      float m1 = fmaxf(fmaxf(red[4], red[5]), fmaxf(red[6], red[7]));
      atomicMax((int*)wsf + 0, __float_as_int(m));
      atomicMax((int*)wsf + 1, __float_as_int(m1));
    }
  }
}

__global__ void init_ws_kernel(int* ws) {
  if (threadIdx.x < 2) ws[threadIdx.x] = 0;
}

// ---------------- stage-2: unchanged from R10 (isolates the stage1 delta) ----------------
template <int RM>
__global__ __launch_bounds__(TB) void write_kernel(const float* __restrict__ inputs,
                                                   const float* __restrict__ mask,
                                                   const float* __restrict__ wsf,
                                                   float* __restrict__ out) {
  __shared__ __align__(16) float sY[W + 1], sY1[W + 1], sM0[NN], sMB[NN];
  __shared__ __align__(16) float sF[NN], sB[NN];
  const int row = blockIdx.x;
  const int r = row & (NR - 1);
  const int tid = threadIdx.x;

  const float* Yg = inputs + (long long)row * W;
  const float* m0 = mask + (long long)r * NN;
  const float* mb = mask + (long long)row * NN;
  for (int k = tid; k < W; k += TB) sY[k] = Yg[k];
  for (int k = tid; k < NN; k += TB) { sM0[k] = m0[k]; sMB[k] = mb[k]; }

  float invX, invX1;
  if (RM == 0) {
    invX  = 1.0f / __int_as_float(((const int*)wsf)[0]);
    invX1 = 1.0f / __int_as_float(((const int*)wsf)[1]);
  } else {
    const int* slots = (const int*)wsf;
    float m = 0.f, m1 = 0.f;
#pragma unroll
    for (int i = 0; i < NSLOT; ++i) {
      m  = fmaxf(m,  __int_as_float(slots[i]));
      m1 = fmaxf(m1, __int_as_float(slots[NSLOT + i]));
    }
    invX = 1.0f / m;
    invX1 = 1.0f / m1;
  }
  __syncthreads();

  if (tid < 2 * NCH) {   // chunked sum scans
    const int arr = tid / NCH;
    const int ch  = tid - arr * NCH;
    const int cs  = ch * 28;
    const int n   = (ch == NCH - 1) ? (NN - cs) : 28;
    if (arr == 0) {
      float run = 0.f;
      for (int i = 0; i < n; ++i) { float v = sMB[cs + i]; run += v * v; sF[cs + i] = run; }
    } else {
      float run = 0.f;
      for (int i = n - 1; i >= 0; --i) { float v = sMB[cs + i]; run += v * v; sB[cs + i] = run; }
    }
  }
  __syncthreads();

  for (int j = tid; j < W; j += TB) {
    int lo = j - (BANDS - 1); if (lo < 0) lo = 0;
    int hi = j;               if (hi > NN - 1) hi = NN - 1;
    const int a = lo / 28, b = hi / 28;
    float slide;
    if (a == b) {
      slide = (lo == a * 28) ? sF[hi] : sB[lo];
    } else {
      slide = sB[lo] + sF[hi];
    }
    sY1[j] = sY[j] * (1.0f / (slide + 1.0f));
  }
  __syncthreads();

  f32x4* outX  = reinterpret_cast<f32x4*>(out) + (long long)row * V4_PER_ROW;
  f32x4* outX1 = reinterpret_cast<f32x4*>(out + OUT_HALF) + (long long)row * V4_PER_ROW;
  for (int idx = tid; idx < V4_PER_ROW; idx += TB) {
    int c = idx / 7;
    int q = idx - c * 7;
    int j0 = c + q * 4;
    float mm = sM0[c];
    f32x4 vx, vx1;
    vx.x  = (mm * sY[j0 + 0]) * invX;
    vx.y  = (mm * sY[j0 + 1]) * invX;
    vx.z  = (mm * sY[j0 + 2]) * invX;
    vx.w  = (mm * sY[j0 + 3]) * invX;
    vx1.x = (mm * sY1[j0 + 0]) * invX1;
    vx1.y = (mm * sY1[j0 + 1]) * invX1;
    vx1.z = (mm * sY1[j0 + 2]) * invX1;
    vx1.w = (mm * sY1[j0 + 3]) * invX1;
    outX[idx]  = vx;
    outX1[idx] = vx1;
  }
}

extern "C" void kernel_launch(void* const* d_in, const int* in_sizes, int n_in,
                              void* d_out, int out_size, void* d_ws, size_t ws_size,
                              hipStream_t stream) {
  const float* inputs = (const float*)d_in[0];
  const float* mask   = (const float*)d_in[1];
  float* wsf = (float*)d_ws;
  float* out = (float*)d_out;

  const size_t need_slots = (size_t)(2 * NSLOT) * sizeof(int);   // 512 B

  if (ws_size >= need_slots) {
    hipLaunchKernelGGL(stage1_kernel<1>, dim3(NR), dim3(TB), 0, stream, inputs, mask, wsf);
    hipLaunchKernelGGL(write_kernel<1>, dim3(ROWS), dim3(TB), 0, stream, inputs, mask, wsf, out);
  } else {
    hipLaunchKernelGGL(init_ws_kernel, dim3(1), dim3(64), 0, stream, (int*)d_ws);
    hipLaunchKernelGGL(stage1_kernel<0>, dim3(NR), dim3(TB), 0, stream, inputs, mask, wsf);
    hipLaunchKernelGGL(write_kernel<0>, dim3(ROWS), dim3(TB), 0, stream, inputs, mask, wsf, out);
  }
}